// Round 1
// baseline (1669.978 us; speedup 1.0000x reference)
//
#include <hip/hip_runtime.h>
#include <math.h>

#define NMS_TH 0.3f

#define N_OBJ 512
#define N_CLS 151
#define REL_DIM 4096
#define N_REL 65536
#define N_RELCLS 51

#define BM 64
#define NKT (REL_DIM / 64)   /* 64 K-steps of 64 */

#define OUT_PRED_OFF (N_OBJ * N_CLS)          /* 77312 */
#define OUT_REL_OFF  (OUT_PRED_OFF + N_OBJ)   /* 77824 */

#define NMS_BLOCKS 150
#define COPY_BLOCKS 8
#define GEMM_BLOCK0 (NMS_BLOCKS + COPY_BLOCKS)
#define GEMM_BLOCKS (N_REL / BM)              /* 1024 */

#define WS_WBF_OFF (1u << 20)   /* bf16 W at ws+1MB; keep_ws (309KB) at ws+0 */
#define WPAD 64                 /* w rows padded 51 -> 64 (pad rows zeroed) */

typedef __attribute__((ext_vector_type(8))) short bf16x8;
typedef __attribute__((ext_vector_type(4))) float f32x4;

struct NmsS {
    float4 bx[N_OBJ];
    float4 sbx[N_OBJ];
    float  sc[N_OBJ];
    float  sarea[N_OBJ];
    int    order[N_OBJ];
    int    act[N_OBJ];
};  /* 24.6 KB; GEMM path uses no LDS -> occupancy is VGPR-limited (4 blocks/CU) */

__device__ __forceinline__ short bf16_rne(float f) {
    unsigned u = __builtin_bit_cast(unsigned, f);
    unsigned r = (u + 0x7fffu + ((u >> 16) & 1u)) >> 16;
    return (short)r;
}
__device__ __forceinline__ bf16x8 pack8(float4 x, float4 y) {
    bf16x8 r;
    r[0] = bf16_rne(x.x); r[1] = bf16_rne(x.y); r[2] = bf16_rne(x.z); r[3] = bf16_rne(x.w);
    r[4] = bf16_rne(y.x); r[5] = bf16_rne(y.y); r[6] = bf16_rne(y.z); r[7] = bf16_rne(y.w);
    return r;
}
__device__ __forceinline__ float iou_f(float4 a, float aa, float4 b, float ab) {
    float xx1 = fmaxf(a.x, b.x), yy1 = fmaxf(a.y, b.y);
    float xx2 = fminf(a.z, b.z), yy2 = fminf(a.w, b.w);
    float w = fmaxf(xx2 - xx1 + 1.0f, 0.0f);
    float h = fmaxf(yy2 - yy1 + 1.0f, 0.0f);
    float inter = w * h;
    return inter / (aa + ab - inter);
}

/* one-shot: w (51x4096 f32) -> bf16, zero-padded to 64 rows, into workspace */
__global__ __launch_bounds__(256)
void conv_w(const float* __restrict__ w, short* __restrict__ wbf)
{
    int g = blockIdx.x * 256 + threadIdx.x;   /* 8 elems per thread */
    int base = g * 8;                          /* < WPAD*REL_DIM */
    int row = base >> 12;                      /* / REL_DIM */
    bf16x8 v = (bf16x8){0, 0, 0, 0, 0, 0, 0, 0};
    if (row < N_RELCLS) {
        float4 x = *(const float4*)(w + base);
        float4 y = *(const float4*)(w + base + 4);
        v = pack8(x, y);
    }
    *(bf16x8*)(wbf + base) = v;
}

__global__ __launch_bounds__(256, 4)
void fused1(const float* __restrict__ logits, const float* __restrict__ vr,
            const float* __restrict__ boxes, const float* __restrict__ b,
            float* __restrict__ out, int* __restrict__ keep_ws,
            const short* __restrict__ wbf)
{
    __shared__ NmsS S;
    const int bid = blockIdx.x;
    const int tid = threadIdx.x;

    if (bid < NMS_BLOCKS) {
        // ---------------- per-class NMS (class c = bid+1) ----------------
        const int c = bid + 1;
        for (int r = tid; r < N_OBJ; r += 256) {
            const float* lrow = logits + r * N_CLS;
            float m = -INFINITY;
            for (int j = 0; j < N_CLS; j++) m = fmaxf(m, lrow[j]);
            float s = 0.f;
            for (int j = 0; j < N_CLS; j++) s += expf(lrow[j] - m);
            S.sc[r] = expf(lrow[c] - m) / s;
            S.bx[r] = *(const float4*)(boxes + ((size_t)r * N_CLS + c) * 4);
        }
        __syncthreads();
        // stable descending argsort via rank counting
        for (int i = tid; i < N_OBJ; i += 256) {
            float si = S.sc[i];
            int rk = 0;
            for (int j = 0; j < N_OBJ; j++) {
                float sj = S.sc[j];
                rk += (sj > si) || (sj == si && j < i);
            }
            S.order[rk] = i;
        }
        __syncthreads();
        for (int i = tid; i < N_OBJ; i += 256) {
            int o = S.order[i];
            float4 bb = S.bx[o];
            S.sbx[i] = bb;
            S.sarea[i] = (bb.z - bb.x + 1.f) * (bb.w - bb.y + 1.f);
            S.act[i] = 1;
        }
        __syncthreads();
        // greedy suppression; each thread owns sorted slots tid and tid+256
        const int j0 = tid, j1 = tid + 256;
        const float4 b0 = S.sbx[j0], b1 = S.sbx[j1];
        const float  a0r = S.sarea[j0], a1r = S.sarea[j1];
        int a0 = 1, a1 = 1;
        for (int i = 0; i < N_OBJ - 1; i++) {
            if (S.act[i]) {
                float4 bi = S.sbx[i];
                float  ari = S.sarea[i];
                if (j0 > i && a0 && iou_f(bi, ari, b0, a0r) > NMS_TH) { a0 = 0; S.act[j0] = 0; }
                if (j1 > i && a1 && iou_f(bi, ari, b1, a1r) > NMS_TH) { a1 = 0; S.act[j1] = 0; }
            }
            __syncthreads();
        }
        for (int i = tid; i < N_OBJ; i += 256)
            keep_ws[(size_t)c * N_OBJ + S.order[i]] = S.act[i];
    } else if (bid < GEMM_BLOCK0) {
        // ---------------- copy obj_dists2 ----------------
        const float4* src = (const float4*)logits;
        float4* dst = (float4*)out;
        const int n4 = (N_OBJ * N_CLS) / 4;
        for (int i = (bid - NMS_BLOCKS) * 256 + tid; i < n4; i += COPY_BLOCKS * 256)
            dst[i] = src[i];
    } else {
        // ---------------- rel_dists GEMM: direct global->reg fragments ----------------
        // A (vr) has ZERO intra-block reuse -> no LDS, no barriers. Each lane's
        // MFMA A-fragment is 8 contiguous f32 of its row: 2x dwordx4 + in-reg cvt.
        // B is preconverted bf16 (417KB valid, L1/L2-resident), loaded as fragments.
        const int gb = bid - GEMM_BLOCK0;
        const size_t row0 = (size_t)gb * BM;
        const int wv = tid >> 6, lane = tid & 63;
        const int lcol = lane & 15, quad = lane >> 4;

        const float* Ap = vr + ((size_t)row0 + wv * 16 + lcol) * REL_DIM + quad * 8;
        const short* Wp = wbf + (size_t)lcol * REL_DIM + quad * 8;

        f32x4 acc[4];
#pragma unroll
        for (int nt = 0; nt < 4; nt++) acc[nt] = (f32x4){0.f, 0.f, 0.f, 0.f};

        /* A fragment regs for current K-step: ks0 = {a0,a1}, ks1 = {a2,a3} */
        float4 a0 = *(const float4*)(Ap + 0);
        float4 a1 = *(const float4*)(Ap + 4);
        float4 a2 = *(const float4*)(Ap + 32);
        float4 a3 = *(const float4*)(Ap + 36);

        for (int kt = 0; kt < NKT - 1; kt++) {
            /* prefetch next K-step's A (one step ahead covers ~900cy HBM latency) */
            const float* An = Ap + (size_t)(kt + 1) * 64;
            float4 n0 = *(const float4*)(An + 0);
            float4 n1 = *(const float4*)(An + 4);
            float4 n2 = *(const float4*)(An + 32);
            float4 n3 = *(const float4*)(An + 36);

            const short* Wk = Wp + (size_t)kt * 64;
            bf16x8 af0 = pack8(a0, a1);
#pragma unroll
            for (int nt = 0; nt < 4; nt++) {
                bf16x8 bfr = *(const bf16x8*)(Wk + nt * 16 * REL_DIM);
                acc[nt] = __builtin_amdgcn_mfma_f32_16x16x32_bf16(af0, bfr, acc[nt], 0, 0, 0);
            }
            bf16x8 af1 = pack8(a2, a3);
#pragma unroll
            for (int nt = 0; nt < 4; nt++) {
                bf16x8 bfr = *(const bf16x8*)(Wk + nt * 16 * REL_DIM + 32);
                acc[nt] = __builtin_amdgcn_mfma_f32_16x16x32_bf16(af1, bfr, acc[nt], 0, 0, 0);
            }
            a0 = n0; a1 = n1; a2 = n2; a3 = n3;
        }
        {   /* last K-step (no prefetch) */
            const short* Wk = Wp + (size_t)(NKT - 1) * 64;
            bf16x8 af0 = pack8(a0, a1);
#pragma unroll
            for (int nt = 0; nt < 4; nt++) {
                bf16x8 bfr = *(const bf16x8*)(Wk + nt * 16 * REL_DIM);
                acc[nt] = __builtin_amdgcn_mfma_f32_16x16x32_bf16(af0, bfr, acc[nt], 0, 0, 0);
            }
            bf16x8 af1 = pack8(a2, a3);
#pragma unroll
            for (int nt = 0; nt < 4; nt++) {
                bf16x8 bfr = *(const bf16x8*)(Wk + nt * 16 * REL_DIM + 32);
                acc[nt] = __builtin_amdgcn_mfma_f32_16x16x32_bf16(af1, bfr, acc[nt], 0, 0, 0);
            }
        }

        // epilogue: C/D layout col=lane&15, row=quad*4+reg (m89-verified)
        float* orel = out + OUT_REL_OFF;
#pragma unroll
        for (int nt = 0; nt < 4; nt++) {
            int col = nt * 16 + lcol;
            if (col < N_RELCLS) {
                float bb = b[col];
#pragma unroll
                for (int r2 = 0; r2 < 4; r2++) {
                    size_t row = row0 + wv * 16 + quad * 4 + r2;
                    orel[row * N_RELCLS + col] = acc[nt][r2] + bb;
                }
            }
        }
    }
}

__global__ __launch_bounds__(256)
void pred_kernel(const float* __restrict__ logits, const int* __restrict__ keep_ws,
                 float* __restrict__ out)
{
    int r = blockIdx.x * 256 + threadIdx.x;
    if (r >= N_OBJ) return;
    const float* lrow = logits + r * N_CLS;
    float m = -INFINITY;
    for (int j = 0; j < N_CLS; j++) m = fmaxf(m, lrow[j]);
    float s = 0.f;
    for (int j = 0; j < N_CLS; j++) s += expf(lrow[j] - m);
    float bestv = -1.f;
    int bestc = 1;
    for (int c = 1; c < N_CLS; c++) {
        float p = keep_ws[(size_t)c * N_OBJ + r] ? (expf(lrow[c] - m) / s) : 0.f;
        if (p > bestv) { bestv = p; bestc = c; }  // strict > => first-max (argmax semantics)
    }
    out[OUT_PRED_OFF + r] = (float)bestc;
}

extern "C" void kernel_launch(void* const* d_in, const int* in_sizes, int n_in,
                              void* d_out, int out_size, void* d_ws, size_t ws_size,
                              hipStream_t stream)
{
    const float* logits = (const float*)d_in[0];
    const float* vr     = (const float*)d_in[1];
    const float* boxes  = (const float*)d_in[2];
    const float* w      = (const float*)d_in[3];
    const float* b      = (const float*)d_in[4];
    float* out = (float*)d_out;
    int* keep_ws = (int*)d_ws;
    short* wbf = (short*)((char*)d_ws + WS_WBF_OFF);

    conv_w<<<(WPAD * REL_DIM / 8) / 256, 256, 0, stream>>>(w, wbf);

    const int grid = GEMM_BLOCK0 + GEMM_BLOCKS; /* 150 nms + 8 copy + 1024 gemm */
    fused1<<<grid, 256, 0, stream>>>(logits, vr, boxes, b, out, keep_ws, wbf);
    pred_kernel<<<2, 256, 0, stream>>>(logits, keep_ws, out);
}